// Round 4
// baseline (592.463 us; speedup 1.0000x reference)
//
#include <hip/hip_runtime.h>
#include <math.h>

#define HDIM 256

typedef float floatx4 __attribute__((ext_vector_type(4)));
typedef __bf16 bf16x8 __attribute__((ext_vector_type(8)));
typedef unsigned short ushortx4 __attribute__((ext_vector_type(4)));

#define AS1C(p) ((const __attribute__((address_space(1))) void*)(p))
#define AS3(p)  ((__attribute__((address_space(3))) void*)(p))

__device__ inline unsigned short bf16_rn(float f) {
  unsigned u = __float_as_uint(f);
  return (unsigned short)((u + 0x7FFFu + ((u >> 16) & 1u)) >> 16);
}

__device__ inline void split_f32(float f, unsigned short& h, unsigned short& l) {
  unsigned short hb = bf16_rn(f);
  float hf = __uint_as_float(((unsigned)hb) << 16);
  h = hb;
  l = bf16_rn(f - hf);
}

// ---------------- weight prep: W[K][256] fp32 -> Wt_hi/Wt_lo [256][K] bf16 ----------------

__global__ __launch_bounds__(256)
void prep_w_kernel(const float* __restrict__ W, unsigned short* __restrict__ WH,
                   unsigned short* __restrict__ WL, int kshift) {
  int idx = blockIdx.x * 256 + threadIdx.x;
  int K = 1 << kshift;
  if (idx >= (K << 8)) return;
  int c = idx >> kshift;
  int k = idx & (K - 1);
  float f = W[(size_t)k * HDIM + c];
  unsigned short h, l;
  split_f32(f, h, l);
  WH[idx] = h;
  WL[idx] = l;
}

// ---------------- CSR build ----------------

__global__ __launch_bounds__(256)
void deg_count_kernel(const int* __restrict__ ei, int* __restrict__ deg, int E) {
  int e = blockIdx.x * 256 + threadIdx.x;
  if (e < E) atomicAdd(&deg[ei[E + e]], 1);
}

__global__ __launch_bounds__(256)
void dinv_kernel(const int* __restrict__ deg, float* __restrict__ dinv, int n) {
  int i = blockIdx.x * 256 + threadIdx.x;
  if (i < n) dinv[i] = 1.0f / sqrtf((float)deg[i] + 1.0f);
}

__global__ __launch_bounds__(256)
void block_sum_kernel(const int* __restrict__ deg, int* __restrict__ bsum, int n) {
  __shared__ int sm[256];
  int t = threadIdx.x;
  int idx = blockIdx.x * 256 + t;
  sm[t] = (idx < n) ? deg[idx] : 0;
  __syncthreads();
  for (int off = 128; off > 0; off >>= 1) {
    if (t < off) sm[t] += sm[t + off];
    __syncthreads();
  }
  if (t == 0) bsum[blockIdx.x] = sm[0];
}

__global__ __launch_bounds__(256)
void scan_bsums_kernel(const int* __restrict__ bsum, int* __restrict__ boff,
                       int* __restrict__ rowptr, int nb, int n) {
  __shared__ int sm[256];
  int t = threadIdx.x;
  int v = (t < nb) ? bsum[t] : 0;
  sm[t] = v;
  __syncthreads();
  for (int off = 1; off < 256; off <<= 1) {
    int a = (t >= off) ? sm[t - off] : 0;
    __syncthreads();
    sm[t] += a;
    __syncthreads();
  }
  if (t < nb) boff[t] = sm[t] - v;
  if (t == 255) rowptr[n] = sm[255];
}

__global__ __launch_bounds__(256)
void scan_final_kernel(const int* __restrict__ deg, const int* __restrict__ boff,
                       int* __restrict__ rowptr, int* __restrict__ cursor, int n) {
  __shared__ int sm[256];
  int t = threadIdx.x;
  int idx = blockIdx.x * 256 + t;
  int v = (idx < n) ? deg[idx] : 0;
  sm[t] = v;
  __syncthreads();
  for (int off = 1; off < 256; off <<= 1) {
    int a = (t >= off) ? sm[t - off] : 0;
    __syncthreads();
    sm[t] += a;
    __syncthreads();
  }
  int excl = sm[t] - v + boff[blockIdx.x];
  if (idx < n) { rowptr[idx] = excl; cursor[idx] = excl; }
}

__global__ __launch_bounds__(256)
void fill_csr_kernel(const int* __restrict__ ei, int* __restrict__ cursor,
                     int* __restrict__ col, int E) {
  int e = blockIdx.x * 256 + threadIdx.x;
  if (e < E) {
    int s = ei[e];
    int d = ei[E + e];
    int p = atomicAdd(&cursor[d], 1);
    col[p] = s;
  }
}

// ---------------- GEMM 1: A fp32 (split in-kernel), tile 128x128, writes planes ----------------

template<bool BIAS, bool RELU>
__global__ __launch_bounds__(256, 3)
void mfma_gemm_splitA(const float* __restrict__ A,
                      const unsigned short* __restrict__ WH,
                      const unsigned short* __restrict__ WL,
                      const float* __restrict__ bias,
                      unsigned short* __restrict__ CH, unsigned short* __restrict__ CL,
                      int M, int K) {
  __shared__ __align__(16) unsigned short AsH[128 * 40];
  __shared__ __align__(16) unsigned short AsL[128 * 40];
  __shared__ __align__(16) unsigned short BsH[4096];
  __shared__ __align__(16) unsigned short BsL[4096];

  const int tid = threadIdx.x;
  const int w = tid >> 6;
  const int l = tid & 63;
  const int l15 = l & 15;
  const int quad = l >> 4;
  const int wm = w & 1;
  const int wn = w >> 1;
  const int bm = blockIdx.y * 128;
  const int bn = blockIdx.x * 128;

  floatx4 acc[4][4];
#pragma unroll
  for (int i = 0; i < 4; ++i)
#pragma unroll
    for (int j = 0; j < 4; ++j) acc[i][j] = (floatx4){0.f, 0.f, 0.f, 0.f};

  for (int k0 = 0; k0 < K; k0 += 32) {
    float4 av[4];
#pragma unroll
    for (int i = 0; i < 4; ++i) {
      int chunk = i * 256 + tid;
      int row = chunk >> 3;
      int kc4 = chunk & 7;
      int grow = bm + row;
      if (grow > M - 1) grow = M - 1;
      av[i] = *(const float4*)(A + (size_t)grow * K + k0 + kc4 * 4);
    }

    __syncthreads();

#pragma unroll
    for (int j = 0; j < 2; ++j) {
      int L = j * 256 + w * 64 + l;
      int kc = L >> 7;
      int colL = L & 127;
      const unsigned short* gH = WH + (size_t)(bn + colL) * K + k0 + kc * 8;
      const unsigned short* gL = WL + (size_t)(bn + colL) * K + k0 + kc * 8;
      __builtin_amdgcn_global_load_lds(AS1C(gH), AS3(&BsH[(j * 256 + w * 64) * 8]), 16, 0, 0);
      __builtin_amdgcn_global_load_lds(AS1C(gL), AS3(&BsL[(j * 256 + w * 64) * 8]), 16, 0, 0);
    }

#pragma unroll
    for (int i = 0; i < 4; ++i) {
      int chunk = i * 256 + tid;
      int row = chunk >> 3;
      int kc4 = chunk & 7;
      unsigned short h0, h1, h2, h3, l0, l1, l2, l3;
      split_f32(av[i].x, h0, l0);
      split_f32(av[i].y, h1, l1);
      split_f32(av[i].z, h2, l2);
      split_f32(av[i].w, h3, l3);
      ushortx4 hv = {h0, h1, h2, h3};
      ushortx4 lv = {l0, l1, l2, l3};
      *(ushortx4*)&AsH[row * 40 + kc4 * 4] = hv;
      *(ushortx4*)&AsL[row * 40 + kc4 * 4] = lv;
    }

    __syncthreads();

    bf16x8 aH[4], aL[4];
#pragma unroll
    for (int fi = 0; fi < 4; ++fi) {
      int row = wm * 64 + fi * 16 + l15;
      aH[fi] = *(const bf16x8*)&AsH[row * 40 + quad * 8];
      aL[fi] = *(const bf16x8*)&AsL[row * 40 + quad * 8];
    }
#pragma unroll
    for (int fj = 0; fj < 4; ++fj) {
      int colL = wn * 64 + fj * 16 + l15;
      int cidx = quad * 128 + colL;
      bf16x8 bh = *(const bf16x8*)&BsH[cidx * 8];
      bf16x8 bl = *(const bf16x8*)&BsL[cidx * 8];
#pragma unroll
      for (int fi = 0; fi < 4; ++fi) {
        floatx4 t = acc[fi][fj];
        t = __builtin_amdgcn_mfma_f32_16x16x32_bf16(aH[fi], bl, t, 0, 0, 0);
        t = __builtin_amdgcn_mfma_f32_16x16x32_bf16(aL[fi], bh, t, 0, 0, 0);
        t = __builtin_amdgcn_mfma_f32_16x16x32_bf16(aH[fi], bh, t, 0, 0, 0);
        acc[fi][fj] = t;
      }
    }
  }

  float bcol[4];
#pragma unroll
  for (int fj = 0; fj < 4; ++fj)
    bcol[fj] = BIAS ? bias[bn + wn * 64 + fj * 16 + l15] : 0.f;

#pragma unroll
  for (int fi = 0; fi < 4; ++fi) {
    int rb = bm + wm * 64 + fi * 16 + quad * 4;
#pragma unroll
    for (int r = 0; r < 4; ++r) {
      int row = rb + r;
      if (row < M) {
        size_t base = (size_t)row * HDIM + bn + wn * 64 + l15;
#pragma unroll
        for (int fj = 0; fj < 4; ++fj) {
          float v = acc[fi][fj][r] + bcol[fj];
          if (RELU) v = fmaxf(v, 0.f);
          unsigned short h, lo;
          split_f32(v, h, lo);
          CH[base + fj * 16] = h;
          CL[base + fj * 16] = lo;
        }
      }
    }
  }
}

// ---------------- GEMM 2x: A = hi/lo planes, tile 64x256, BK=32, 4 blocks/CU ----------------
// 256 threads = 4 waves, each wave 64x64 (acc[4][4] = 64 VGPR). A read once (BN=256),
// in-place safe (block reads only its own 64 rows, writes after k-loop completes).

template<bool BIAS, bool RELU, bool SPLIT_OUT>
__global__ __launch_bounds__(256, 4)
void mfma_gemm2x(const unsigned short* __restrict__ AH, const unsigned short* __restrict__ AL,
                 const unsigned short* __restrict__ WH, const unsigned short* __restrict__ WL,
                 const float* __restrict__ bias,
                 float* __restrict__ C, unsigned short* __restrict__ CH,
                 unsigned short* __restrict__ CL, int M) {
  __shared__ __align__(16) unsigned short AsH[64 * 32];   // 256 chunks: row*4 + kc (swizzled)
  __shared__ __align__(16) unsigned short AsL[64 * 32];
  __shared__ __align__(16) unsigned short BsH[32 * 256];  // 1024 chunks: kc*256 + col
  __shared__ __align__(16) unsigned short BsL[32 * 256];

  const int tid = threadIdx.x;
  const int w = tid >> 6;      // wave = col stripe of 64
  const int l = tid & 63;
  const int l15 = l & 15;
  const int quad = l >> 4;
  const int bm = blockIdx.x * 64;

  floatx4 acc[4][4];
#pragma unroll
  for (int i = 0; i < 4; ++i)
#pragma unroll
    for (int j = 0; j < 4; ++j) acc[i][j] = (floatx4){0.f, 0.f, 0.f, 0.f};

  for (int k0 = 0; k0 < HDIM; k0 += 32) {
    __syncthreads();  // prior tile's LDS reads done

    // A: 256 chunks per plane, 1 per thread
    {
      int L = tid;
      int row = L >> 2;
      int kcL = L & 3;
      int kc = kcL ^ (row & 3) ^ ((row >> 2) & 3);
      int grow = bm + row;
      if (grow > M - 1) grow = M - 1;
      const unsigned short* gH = AH + (size_t)grow * HDIM + k0 + kc * 8;
      const unsigned short* gL = AL + (size_t)grow * HDIM + k0 + kc * 8;
      __builtin_amdgcn_global_load_lds(AS1C(gH), AS3(&AsH[(w * 64) * 8]), 16, 0, 0);
      __builtin_amdgcn_global_load_lds(AS1C(gL), AS3(&AsL[(w * 64) * 8]), 16, 0, 0);
    }
    // B: 1024 chunks per plane, 4 per thread
#pragma unroll
    for (int j = 0; j < 4; ++j) {
      int L = j * 256 + tid;
      int kc = L >> 8;
      int colL = L & 255;
      const unsigned short* gH = WH + (size_t)colL * HDIM + k0 + kc * 8;
      const unsigned short* gL = WL + (size_t)colL * HDIM + k0 + kc * 8;
      __builtin_amdgcn_global_load_lds(AS1C(gH), AS3(&BsH[(j * 256 + w * 64) * 8]), 16, 0, 0);
      __builtin_amdgcn_global_load_lds(AS1C(gL), AS3(&BsL[(j * 256 + w * 64) * 8]), 16, 0, 0);
    }

    __syncthreads();  // vmcnt drained

    bf16x8 aH[4], aL[4];
#pragma unroll
    for (int fi = 0; fi < 4; ++fi) {
      int r = fi * 16 + l15;
      int sw = quad ^ (r & 3) ^ ((r >> 2) & 3);
      aH[fi] = *(const bf16x8*)&AsH[(r * 4 + sw) * 8];
      aL[fi] = *(const bf16x8*)&AsL[(r * 4 + sw) * 8];
    }
#pragma unroll
    for (int fj = 0; fj < 4; ++fj) {
      int colL = w * 64 + fj * 16 + l15;
      int cidx = quad * 256 + colL;
      bf16x8 bh = *(const bf16x8*)&BsH[cidx * 8];
      bf16x8 bl = *(const bf16x8*)&BsL[cidx * 8];
#pragma unroll
      for (int fi = 0; fi < 4; ++fi) {
        floatx4 t = acc[fi][fj];
        t = __builtin_amdgcn_mfma_f32_16x16x32_bf16(aH[fi], bl, t, 0, 0, 0);
        t = __builtin_amdgcn_mfma_f32_16x16x32_bf16(aL[fi], bh, t, 0, 0, 0);
        t = __builtin_amdgcn_mfma_f32_16x16x32_bf16(aH[fi], bh, t, 0, 0, 0);
        acc[fi][fj] = t;
      }
    }
  }

  float bcol[4];
#pragma unroll
  for (int fj = 0; fj < 4; ++fj)
    bcol[fj] = BIAS ? bias[w * 64 + fj * 16 + l15] : 0.f;

#pragma unroll
  for (int fi = 0; fi < 4; ++fi) {
    int rb = bm + fi * 16 + quad * 4;
#pragma unroll
    for (int r = 0; r < 4; ++r) {
      int row = rb + r;
      if (row < M) {
        size_t base = (size_t)row * HDIM + w * 64 + l15;
        if (SPLIT_OUT) {
#pragma unroll
          for (int fj = 0; fj < 4; ++fj) {
            float v = acc[fi][fj][r] + bcol[fj];
            if (RELU) v = fmaxf(v, 0.f);
            unsigned short h, lo;
            split_f32(v, h, lo);
            CH[base + fj * 16] = h;
            CL[base + fj * 16] = lo;
          }
        } else {
#pragma unroll
          for (int fj = 0; fj < 4; ++fj) {
            float v = acc[fi][fj][r] + bcol[fj];
            if (RELU) v = fmaxf(v, 0.f);
            C[base + fj * 16] = v;
          }
        }
      }
    }
  }
}

// ---------------- GCN aggregation: batched MLP=8 gather, plane output ----------------

__global__ __launch_bounds__(256)
void aggregate3_kernel(const float* __restrict__ t, const float* __restrict__ dinv,
                       const int* __restrict__ rowptr, const int* __restrict__ col,
                       const float* __restrict__ bias,
                       unsigned short* __restrict__ OH, unsigned short* __restrict__ OL, int n) {
  int gw = (int)((blockIdx.x * 256 + threadIdx.x) >> 6);
  int lane = threadIdx.x & 63;
  if (gw >= n) return;
  float di = dinv[gw];
  float4 v = ((const float4*)(t + (size_t)gw * HDIM))[lane];
  float ss = di * di;
  float a0 = v.x * ss, a1 = v.y * ss, a2 = v.z * ss, a3 = v.w * ss;
  int e0 = rowptr[gw], e1 = rowptr[gw + 1];

  for (int base = e0; base < e1; base += 8) {
    int m = e1 - base;
    if (m > 8) m = 8;
    float4 rows[8];
    float wg[8];
#pragma unroll
    for (int i = 0; i < 8; ++i) {
      if (i < m) {
        int s = __builtin_amdgcn_readfirstlane(col[base + i]);
        wg[i] = dinv[s] * di;
        rows[i] = ((const float4*)(t + (size_t)s * HDIM))[lane];
      }
    }
#pragma unroll
    for (int i = 0; i < 8; ++i) {
      if (i < m) {
        a0 = fmaf(rows[i].x, wg[i], a0);
        a1 = fmaf(rows[i].y, wg[i], a1);
        a2 = fmaf(rows[i].z, wg[i], a2);
        a3 = fmaf(rows[i].w, wg[i], a3);
      }
    }
  }

  float4 bb = ((const float4*)bias)[lane];
  float r0 = fmaxf(a0 + bb.x, 0.f);
  float r1 = fmaxf(a1 + bb.y, 0.f);
  float r2 = fmaxf(a2 + bb.z, 0.f);
  float r3 = fmaxf(a3 + bb.w, 0.f);
  unsigned short h0, h1, h2, h3, l0, l1, l2, l3;
  split_f32(r0, h0, l0);
  split_f32(r1, h1, l1);
  split_f32(r2, h2, l2);
  split_f32(r3, h3, l3);
  ((ushortx4*)(OH + (size_t)gw * HDIM))[lane] = (ushortx4){h0, h1, h2, h3};
  ((ushortx4*)(OL + (size_t)gw * HDIM))[lane] = (ushortx4){l0, l1, l2, l3};
}

// ---------------- row softmax, one wave per row, in-place safe ----------------

__global__ __launch_bounds__(256)
void softmax_kernel(const float* __restrict__ logits, float* __restrict__ outp, int n) {
  int gw = (int)((blockIdx.x * 256 + threadIdx.x) >> 6);
  int lane = threadIdx.x & 63;
  if (gw >= n) return;
  float4 v = ((const float4*)(logits + (size_t)gw * HDIM))[lane];
  float m = fmaxf(fmaxf(v.x, v.y), fmaxf(v.z, v.w));
#pragma unroll
  for (int off = 1; off < 64; off <<= 1) m = fmaxf(m, __shfl_xor(m, off));
  float ex = expf(v.x - m), ey = expf(v.y - m), ez = expf(v.z - m), ew = expf(v.w - m);
  float s = ex + ey + ez + ew;
#pragma unroll
  for (int off = 1; off < 64; off <<= 1) s += __shfl_xor(s, off);
  float inv = 1.0f / s;
  ((float4*)(outp + (size_t)gw * HDIM))[lane] = make_float4(ex * inv, ey * inv, ez * inv, ew * inv);
}

// ---------------- launch ----------------

extern "C" void kernel_launch(void* const* d_in, const int* in_sizes, int n_in,
                              void* d_out, int out_size, void* d_ws, size_t ws_size,
                              hipStream_t stream) {
  const float* x   = (const float*)d_in[0];
  const int*   ei  = (const int*)d_in[1];
  const float* W1  = (const float*)d_in[2];
  const float* b1  = (const float*)d_in[3];
  const float* Wg1 = (const float*)d_in[4];
  const float* bg1 = (const float*)d_in[5];
  const float* Wg2 = (const float*)d_in[6];
  const float* bg2 = (const float*)d_in[7];
  const float* W2  = (const float*)d_in[8];
  const float* b2  = (const float*)d_in[9];
  const float* W3  = (const float*)d_in[10];
  const float* b3  = (const float*)d_in[11];
  float* out = (float*)d_out;

  const int K1 = in_sizes[2] / HDIM;  // 128
  const int N  = in_sizes[0] / K1;    // 50000
  const int E  = in_sizes[1] / 2;     // 300000

  char* w = (char*)d_ws;
  auto alloc = [&](size_t bytes) -> char* {
    char* p = w;
    w += (bytes + 255) & ~(size_t)255;
    return p;
  };
  unsigned short* PH = (unsigned short*)alloc((size_t)N * HDIM * 2);
  unsigned short* PL = (unsigned short*)alloc((size_t)N * HDIM * 2);
  float* dinv   = (float*)alloc((size_t)N * sizeof(float));
  int*   deg    = (int*)alloc((size_t)N * sizeof(int));
  int*   rowptr = (int*)alloc((size_t)(N + 1) * sizeof(int));
  int*   cursor = (int*)alloc((size_t)N * sizeof(int));
  int*   col    = (int*)alloc((size_t)E * sizeof(int));
  const int nb  = (N + 255) / 256;
  int*   bsum   = (int*)alloc((size_t)nb * sizeof(int));
  int*   boff   = (int*)alloc((size_t)nb * sizeof(int));
  unsigned short* W1tH  = (unsigned short*)alloc((size_t)HDIM * K1 * 2);
  unsigned short* W1tL  = (unsigned short*)alloc((size_t)HDIM * K1 * 2);
  unsigned short* Wg1tH = (unsigned short*)alloc((size_t)HDIM * HDIM * 2);
  unsigned short* Wg1tL = (unsigned short*)alloc((size_t)HDIM * HDIM * 2);
  unsigned short* Wg2tH = (unsigned short*)alloc((size_t)HDIM * HDIM * 2);
  unsigned short* Wg2tL = (unsigned short*)alloc((size_t)HDIM * HDIM * 2);
  unsigned short* W2tH  = (unsigned short*)alloc((size_t)HDIM * HDIM * 2);
  unsigned short* W2tL  = (unsigned short*)alloc((size_t)HDIM * HDIM * 2);
  unsigned short* W3tH  = (unsigned short*)alloc((size_t)HDIM * HDIM * 2);
  unsigned short* W3tL  = (unsigned short*)alloc((size_t)HDIM * HDIM * 2);

  const int ge = (E + 255) / 256;
  const int gn = (N + 255) / 256;
  const int kshift1 = (K1 == 128) ? 7 : 8;

  prep_w_kernel<<<(HDIM * K1 + 255) / 256, 256, 0, stream>>>(W1, W1tH, W1tL, kshift1);
  prep_w_kernel<<<(HDIM * HDIM + 255) / 256, 256, 0, stream>>>(Wg1, Wg1tH, Wg1tL, 8);
  prep_w_kernel<<<(HDIM * HDIM + 255) / 256, 256, 0, stream>>>(Wg2, Wg2tH, Wg2tL, 8);
  prep_w_kernel<<<(HDIM * HDIM + 255) / 256, 256, 0, stream>>>(W2, W2tH, W2tL, 8);
  prep_w_kernel<<<(HDIM * HDIM + 255) / 256, 256, 0, stream>>>(W3, W3tH, W3tL, 8);

  hipMemsetAsync(deg, 0, (size_t)N * sizeof(int), stream);
  deg_count_kernel<<<ge, 256, 0, stream>>>(ei, deg, E);
  dinv_kernel<<<gn, 256, 0, stream>>>(deg, dinv, N);
  block_sum_kernel<<<nb, 256, 0, stream>>>(deg, bsum, N);
  scan_bsums_kernel<<<1, 256, 0, stream>>>(bsum, boff, rowptr, nb, N);
  scan_final_kernel<<<nb, 256, 0, stream>>>(deg, boff, rowptr, cursor, N);
  fill_csr_kernel<<<ge, 256, 0, stream>>>(ei, cursor, col, E);

  dim3 g1grid(HDIM / 128, (N + 127) / 128);
  const int g2grid = (N + 63) / 64;
  const int gagg = (N + 3) / 4;

  // h0 = relu(x@W1+b1) -> planes P
  mfma_gemm_splitA<true, true><<<g1grid, 256, 0, stream>>>(x, W1tH, W1tL, b1, PH, PL, N, K1);
  // t1 = h0@Wg1 -> out (fp32 scratch)
  mfma_gemm2x<false, false, false><<<g2grid, 256, 0, stream>>>(PH, PL, Wg1tH, Wg1tL, nullptr, out, nullptr, nullptr, N);
  // h1 = relu(agg(t1)+bg1) -> planes P
  aggregate3_kernel<<<gagg, 256, 0, stream>>>(out, dinv, rowptr, col, bg1, PH, PL, N);
  // t2 = h1@Wg2 -> out
  mfma_gemm2x<false, false, false><<<g2grid, 256, 0, stream>>>(PH, PL, Wg2tH, Wg2tL, nullptr, out, nullptr, nullptr, N);
  // h2 = relu(agg(t2)+bg2) -> planes P
  aggregate3_kernel<<<gagg, 256, 0, stream>>>(out, dinv, rowptr, col, bg2, PH, PL, N);
  // h3 = relu(h2@W2+b2) -> planes P (in-place: block reads only its own 64 rows)
  mfma_gemm2x<true, true, true><<<g2grid, 256, 0, stream>>>(PH, PL, W2tH, W2tL, b2, nullptr, PH, PL, N);
  // logits = h3@W3+b3 -> out
  mfma_gemm2x<true, false, false><<<g2grid, 256, 0, stream>>>(PH, PL, W3tH, W3tL, b3, out, nullptr, nullptr, N);
  // softmax in place
  softmax_kernel<<<gagg, 256, 0, stream>>>(out, out, N);
}

// Round 5
// 434.195 us; speedup vs baseline: 1.3645x; 1.3645x over previous
//
#include <hip/hip_runtime.h>
#include <math.h>

#define HDIM 256

typedef float floatx4 __attribute__((ext_vector_type(4)));
typedef __bf16 bf16x8 __attribute__((ext_vector_type(8)));
typedef unsigned short ushortx4 __attribute__((ext_vector_type(4)));

#define AS1C(p) ((const __attribute__((address_space(1))) void*)(p))
#define AS3(p)  ((__attribute__((address_space(3))) void*)(p))

__device__ inline unsigned short bf16_rn(float f) {
  unsigned u = __float_as_uint(f);
  return (unsigned short)((u + 0x7FFFu + ((u >> 16) & 1u)) >> 16);
}

__device__ inline void split_f32(float f, unsigned short& h, unsigned short& l) {
  unsigned short hb = bf16_rn(f);
  float hf = __uint_as_float(((unsigned)hb) << 16);
  h = hb;
  l = bf16_rn(f - hf);
}

// ---------------- weight prep: W[K][256] fp32 -> staged hi/lo bf16 in tile order ----------------
// Staged layout: idx = ((cb*(K/32) + kt)*512 + kc*128 + col), 8 elements per chunk.
// chunk content = W[kt*32 + kc*8 + e][cb*128 + col]  (i.e. W^T row segment)
// -> in-kernel B staging is a fully contiguous per-wave 1KB load.

__global__ __launch_bounds__(256)
void prep_w_staged(const float* __restrict__ W, unsigned short* __restrict__ SH,
                   unsigned short* __restrict__ SL, int K) {
  int idx = blockIdx.x * 256 + threadIdx.x;
  int total = K * 32;             // number of 8-elem chunks (2 cb * K/32 * 512)
  if (idx >= total) return;
  int chunksPerCb = total >> 1;
  int cb = (idx >= chunksPerCb) ? 1 : 0;
  int rem = idx - cb * chunksPerCb;
  int kt = rem >> 9;
  int chunk = rem & 511;
  int kc = chunk >> 7;
  int col = chunk & 127;
  const float* src = W + (size_t)(kt * 32 + kc * 8) * HDIM + cb * 128 + col;
#pragma unroll
  for (int e = 0; e < 8; ++e) {
    unsigned short h, l;
    split_f32(src[(size_t)e * HDIM], h, l);
    SH[(size_t)idx * 8 + e] = h;
    SL[(size_t)idx * 8 + e] = l;
  }
}

// ---------------- CSR build ----------------

__global__ __launch_bounds__(256)
void deg_count_kernel(const int* __restrict__ ei, int* __restrict__ deg, int E) {
  int e = blockIdx.x * 256 + threadIdx.x;
  if (e < E) atomicAdd(&deg[ei[E + e]], 1);
}

__global__ __launch_bounds__(256)
void dinv_kernel(const int* __restrict__ deg, float* __restrict__ dinv, int n) {
  int i = blockIdx.x * 256 + threadIdx.x;
  if (i < n) dinv[i] = 1.0f / sqrtf((float)deg[i] + 1.0f);
}

__global__ __launch_bounds__(256)
void block_sum_kernel(const int* __restrict__ deg, int* __restrict__ bsum, int n) {
  __shared__ int sm[256];
  int t = threadIdx.x;
  int idx = blockIdx.x * 256 + t;
  sm[t] = (idx < n) ? deg[idx] : 0;
  __syncthreads();
  for (int off = 128; off > 0; off >>= 1) {
    if (t < off) sm[t] += sm[t + off];
    __syncthreads();
  }
  if (t == 0) bsum[blockIdx.x] = sm[0];
}

__global__ __launch_bounds__(256)
void scan_bsums_kernel(const int* __restrict__ bsum, int* __restrict__ boff,
                       int* __restrict__ rowptr, int nb, int n) {
  __shared__ int sm[256];
  int t = threadIdx.x;
  int v = (t < nb) ? bsum[t] : 0;
  sm[t] = v;
  __syncthreads();
  for (int off = 1; off < 256; off <<= 1) {
    int a = (t >= off) ? sm[t - off] : 0;
    __syncthreads();
    sm[t] += a;
    __syncthreads();
  }
  if (t < nb) boff[t] = sm[t] - v;
  if (t == 255) rowptr[n] = sm[255];
}

__global__ __launch_bounds__(256)
void scan_final_kernel(const int* __restrict__ deg, const int* __restrict__ boff,
                       int* __restrict__ rowptr, int* __restrict__ cursor, int n) {
  __shared__ int sm[256];
  int t = threadIdx.x;
  int idx = blockIdx.x * 256 + t;
  int v = (idx < n) ? deg[idx] : 0;
  sm[t] = v;
  __syncthreads();
  for (int off = 1; off < 256; off <<= 1) {
    int a = (t >= off) ? sm[t - off] : 0;
    __syncthreads();
    sm[t] += a;
    __syncthreads();
  }
  int excl = sm[t] - v + boff[blockIdx.x];
  if (idx < n) { rowptr[idx] = excl; cursor[idx] = excl; }
}

__global__ __launch_bounds__(256)
void fill_csr_kernel(const int* __restrict__ ei, int* __restrict__ cursor,
                     int* __restrict__ col, int E) {
  int e = blockIdx.x * 256 + threadIdx.x;
  if (e < E) {
    int s = ei[e];
    int d = ei[E + e];
    int p = atomicAdd(&cursor[d], 1);
    col[p] = s;
  }
}

// ---------------- GEMM 1: A fp32 (split in-kernel), tile 128x128, staged B, writes planes ----------------

template<bool BIAS, bool RELU>
__global__ __launch_bounds__(256, 3)
void mfma_gemm_splitA(const float* __restrict__ A,
                      const unsigned short* __restrict__ SWH,
                      const unsigned short* __restrict__ SWL,
                      const float* __restrict__ bias,
                      unsigned short* __restrict__ CH, unsigned short* __restrict__ CL,
                      int M, int K) {
  __shared__ __align__(16) unsigned short AsH[128 * 40];
  __shared__ __align__(16) unsigned short AsL[128 * 40];
  __shared__ __align__(16) unsigned short BsH[4096];
  __shared__ __align__(16) unsigned short BsL[4096];

  const int tid = threadIdx.x;
  const int w = tid >> 6;
  const int l = tid & 63;
  const int l15 = l & 15;
  const int quad = l >> 4;
  const int wm = w & 1;
  const int wn = w >> 1;
  const int bm = blockIdx.y * 128;
  const int bn = blockIdx.x * 128;
  const int ktc = K >> 5;

  floatx4 acc[4][4];
#pragma unroll
  for (int i = 0; i < 4; ++i)
#pragma unroll
    for (int j = 0; j < 4; ++j) acc[i][j] = (floatx4){0.f, 0.f, 0.f, 0.f};

  for (int kt = 0; kt < ktc; ++kt) {
    int k0 = kt * 32;
    float4 av[4];
#pragma unroll
    for (int i = 0; i < 4; ++i) {
      int chunk = i * 256 + tid;
      int row = chunk >> 3;
      int kc4 = chunk & 7;
      int grow = bm + row;
      if (grow > M - 1) grow = M - 1;
      av[i] = *(const float4*)(A + (size_t)grow * K + k0 + kc4 * 4);
    }

    __syncthreads();

    // B: staged contiguous chunks
    size_t wb = ((size_t)(blockIdx.x * ktc + kt)) * 4096;
#pragma unroll
    for (int j = 0; j < 2; ++j) {
      int c = j * 256 + tid;
      __builtin_amdgcn_global_load_lds(AS1C(SWH + wb + (size_t)c * 8),
                                       AS3(&BsH[(j * 256 + w * 64) * 8]), 16, 0, 0);
      __builtin_amdgcn_global_load_lds(AS1C(SWL + wb + (size_t)c * 8),
                                       AS3(&BsL[(j * 256 + w * 64) * 8]), 16, 0, 0);
    }

#pragma unroll
    for (int i = 0; i < 4; ++i) {
      int chunk = i * 256 + tid;
      int row = chunk >> 3;
      int kc4 = chunk & 7;
      unsigned short h0, h1, h2, h3, l0, l1, l2, l3;
      split_f32(av[i].x, h0, l0);
      split_f32(av[i].y, h1, l1);
      split_f32(av[i].z, h2, l2);
      split_f32(av[i].w, h3, l3);
      *(ushortx4*)&AsH[row * 40 + kc4 * 4] = (ushortx4){h0, h1, h2, h3};
      *(ushortx4*)&AsL[row * 40 + kc4 * 4] = (ushortx4){l0, l1, l2, l3};
    }

    __syncthreads();

    bf16x8 aH[4], aL[4];
#pragma unroll
    for (int fi = 0; fi < 4; ++fi) {
      int row = wm * 64 + fi * 16 + l15;
      aH[fi] = *(const bf16x8*)&AsH[row * 40 + quad * 8];
      aL[fi] = *(const bf16x8*)&AsL[row * 40 + quad * 8];
    }
#pragma unroll
    for (int fj = 0; fj < 4; ++fj) {
      int colL = wn * 64 + fj * 16 + l15;
      int cidx = quad * 128 + colL;
      bf16x8 bh = *(const bf16x8*)&BsH[cidx * 8];
      bf16x8 bl = *(const bf16x8*)&BsL[cidx * 8];
#pragma unroll
      for (int fi = 0; fi < 4; ++fi) {
        floatx4 t = acc[fi][fj];
        t = __builtin_amdgcn_mfma_f32_16x16x32_bf16(aH[fi], bl, t, 0, 0, 0);
        t = __builtin_amdgcn_mfma_f32_16x16x32_bf16(aL[fi], bh, t, 0, 0, 0);
        t = __builtin_amdgcn_mfma_f32_16x16x32_bf16(aH[fi], bh, t, 0, 0, 0);
        acc[fi][fj] = t;
      }
    }
  }

  float bcol[4];
#pragma unroll
  for (int fj = 0; fj < 4; ++fj)
    bcol[fj] = BIAS ? bias[bn + wn * 64 + fj * 16 + l15] : 0.f;

#pragma unroll
  for (int fi = 0; fi < 4; ++fi) {
    int rb = bm + wm * 64 + fi * 16 + quad * 4;
#pragma unroll
    for (int r = 0; r < 4; ++r) {
      int row = rb + r;
      if (row < M) {
        size_t base = (size_t)row * HDIM + bn + wn * 64 + l15;
#pragma unroll
        for (int fj = 0; fj < 4; ++fj) {
          float v = acc[fi][fj][r] + bcol[fj];
          if (RELU) v = fmaxf(v, 0.f);
          unsigned short h, lo;
          split_f32(v, h, lo);
          CH[base + fj * 16] = h;
          CL[base + fj * 16] = lo;
        }
      }
    }
  }
}

// ---------------- plane GEMM: A hi/lo planes + staged B, all via global_load_lds ----------------
// Tile 128x128, BK=32, 4 waves x 64x64. Per thread per k-tile: 8x16B global_load_lds, 0 VALU.
// 48 MFMA per wave per k-tile.

template<bool BIAS, bool RELU, bool SPLIT_OUT>
__global__ __launch_bounds__(256, 3)
void mfma_gemm_p(const unsigned short* __restrict__ AH, const unsigned short* __restrict__ AL,
                 const unsigned short* __restrict__ SWH, const unsigned short* __restrict__ SWL,
                 const float* __restrict__ bias,
                 float* __restrict__ C, unsigned short* __restrict__ CH,
                 unsigned short* __restrict__ CL, int M, int K) {
  __shared__ __align__(16) unsigned short AsH[4096];  // 512 chunks: row*4 + swizzled kc
  __shared__ __align__(16) unsigned short AsL[4096];
  __shared__ __align__(16) unsigned short BsH[4096];  // 512 chunks: kc*128 + col
  __shared__ __align__(16) unsigned short BsL[4096];

  const int tid = threadIdx.x;
  const int w = tid >> 6;
  const int l = tid & 63;
  const int l15 = l & 15;
  const int quad = l >> 4;
  const int wm = w & 1;
  const int wn = w >> 1;
  const int bm = blockIdx.y * 128;
  const int bn = blockIdx.x * 128;
  const int ktc = K >> 5;

  floatx4 acc[4][4];
#pragma unroll
  for (int i = 0; i < 4; ++i)
#pragma unroll
    for (int j = 0; j < 4; ++j) acc[i][j] = (floatx4){0.f, 0.f, 0.f, 0.f};

  for (int kt = 0; kt < ktc; ++kt) {
    __syncthreads();  // prior tile's LDS reads complete

    // A: 512 chunks per plane, 2 per thread; store position L holds swizzled kc
#pragma unroll
    for (int i = 0; i < 2; ++i) {
      int L = i * 256 + tid;
      int row = L >> 2;
      int p = L & 3;
      int kc = p ^ (row & 3) ^ ((row >> 2) & 3);
      int grow = bm + row;
      if (grow > M - 1) grow = M - 1;
      const unsigned short* gH = AH + (size_t)grow * K + kt * 32 + kc * 8;
      const unsigned short* gL = AL + (size_t)grow * K + kt * 32 + kc * 8;
      __builtin_amdgcn_global_load_lds(AS1C(gH), AS3(&AsH[(i * 256 + w * 64) * 8]), 16, 0, 0);
      __builtin_amdgcn_global_load_lds(AS1C(gL), AS3(&AsL[(i * 256 + w * 64) * 8]), 16, 0, 0);
    }
    // B: staged contiguous, 512 chunks per plane, 2 per thread
    size_t wb = ((size_t)(blockIdx.x * ktc + kt)) * 4096;
#pragma unroll
    for (int j = 0; j < 2; ++j) {
      int c = j * 256 + tid;
      __builtin_amdgcn_global_load_lds(AS1C(SWH + wb + (size_t)c * 8),
                                       AS3(&BsH[(j * 256 + w * 64) * 8]), 16, 0, 0);
      __builtin_amdgcn_global_load_lds(AS1C(SWL + wb + (size_t)c * 8),
                                       AS3(&BsL[(j * 256 + w * 64) * 8]), 16, 0, 0);
    }

    __syncthreads();  // drains vmcnt before reads

    bf16x8 aH[4], aL[4];
#pragma unroll
    for (int fi = 0; fi < 4; ++fi) {
      int r = wm * 64 + fi * 16 + l15;
      int sw = quad ^ (r & 3) ^ ((r >> 2) & 3);
      aH[fi] = *(const bf16x8*)&AsH[(r * 4 + sw) * 8];
      aL[fi] = *(const bf16x8*)&AsL[(r * 4 + sw) * 8];
    }
#pragma unroll
    for (int fj = 0; fj < 4; ++fj) {
      int colL = wn * 64 + fj * 16 + l15;
      int cidx = quad * 128 + colL;
      bf16x8 bh = *(const bf16x8*)&BsH[cidx * 8];
      bf16x8 bl = *(const bf16x8*)&BsL[cidx * 8];
#pragma unroll
      for (int fi = 0; fi < 4; ++fi) {
        floatx4 t = acc[fi][fj];
        t = __builtin_amdgcn_mfma_f32_16x16x32_bf16(aH[fi], bl, t, 0, 0, 0);
        t = __builtin_amdgcn_mfma_f32_16x16x32_bf16(aL[fi], bh, t, 0, 0, 0);
        t = __builtin_amdgcn_mfma_f32_16x16x32_bf16(aH[fi], bh, t, 0, 0, 0);
        acc[fi][fj] = t;
      }
    }
  }

  float bcol[4];
#pragma unroll
  for (int fj = 0; fj < 4; ++fj)
    bcol[fj] = BIAS ? bias[bn + wn * 64 + fj * 16 + l15] : 0.f;

#pragma unroll
  for (int fi = 0; fi < 4; ++fi) {
    int rb = bm + wm * 64 + fi * 16 + quad * 4;
#pragma unroll
    for (int r = 0; r < 4; ++r) {
      int row = rb + r;
      if (row < M) {
        size_t base = (size_t)row * HDIM + bn + wn * 64 + l15;
        if (SPLIT_OUT) {
#pragma unroll
          for (int fj = 0; fj < 4; ++fj) {
            float v = acc[fi][fj][r] + bcol[fj];
            if (RELU) v = fmaxf(v, 0.f);
            unsigned short h, lo;
            split_f32(v, h, lo);
            CH[base + fj * 16] = h;
            CL[base + fj * 16] = lo;
          }
        } else {
#pragma unroll
          for (int fj = 0; fj < 4; ++fj) {
            float v = acc[fi][fj][r] + bcol[fj];
            if (RELU) v = fmaxf(v, 0.f);
            C[base + fj * 16] = v;
          }
        }
      }
    }
  }
}

// ---------------- GCN aggregation: simple pull gather, plane output ----------------

__global__ __launch_bounds__(256)
void aggregate_p(const float* __restrict__ t, const float* __restrict__ dinv,
                 const int* __restrict__ rowptr, const int* __restrict__ col,
                 const float* __restrict__ bias,
                 unsigned short* __restrict__ OH, unsigned short* __restrict__ OL, int n) {
  int gw = (int)((blockIdx.x * 256 + threadIdx.x) >> 6);
  int lane = threadIdx.x & 63;
  if (gw >= n) return;
  float di = dinv[gw];
  float4 v = ((const float4*)(t + (size_t)gw * HDIM))[lane];
  float ss = di * di;
  float a0 = v.x * ss, a1 = v.y * ss, a2 = v.z * ss, a3 = v.w * ss;
  int e0 = rowptr[gw], e1 = rowptr[gw + 1];
  for (int e = e0; e < e1; ++e) {
    int s = col[e];
    float wgt = dinv[s] * di;
    float4 u = ((const float4*)(t + (size_t)s * HDIM))[lane];
    a0 = fmaf(u.x, wgt, a0);
    a1 = fmaf(u.y, wgt, a1);
    a2 = fmaf(u.z, wgt, a2);
    a3 = fmaf(u.w, wgt, a3);
  }
  float4 bb = ((const float4*)bias)[lane];
  float r0 = fmaxf(a0 + bb.x, 0.f);
  float r1 = fmaxf(a1 + bb.y, 0.f);
  float r2 = fmaxf(a2 + bb.z, 0.f);
  float r3 = fmaxf(a3 + bb.w, 0.f);
  unsigned short h0, h1, h2, h3, l0, l1, l2, l3;
  split_f32(r0, h0, l0);
  split_f32(r1, h1, l1);
  split_f32(r2, h2, l2);
  split_f32(r3, h3, l3);
  ((ushortx4*)(OH + (size_t)gw * HDIM))[lane] = (ushortx4){h0, h1, h2, h3};
  ((ushortx4*)(OL + (size_t)gw * HDIM))[lane] = (ushortx4){l0, l1, l2, l3};
}

// ---------------- row softmax, one wave per row ----------------

__global__ __launch_bounds__(256)
void softmax_kernel(const float* __restrict__ logits, float* __restrict__ outp, int n) {
  int gw = (int)((blockIdx.x * 256 + threadIdx.x) >> 6);
  int lane = threadIdx.x & 63;
  if (gw >= n) return;
  float4 v = ((const float4*)(logits + (size_t)gw * HDIM))[lane];
  float m = fmaxf(fmaxf(v.x, v.y), fmaxf(v.z, v.w));
#pragma unroll
  for (int off = 1; off < 64; off <<= 1) m = fmaxf(m, __shfl_xor(m, off));
  float ex = expf(v.x - m), ey = expf(v.y - m), ez = expf(v.z - m), ew = expf(v.w - m);
  float s = ex + ey + ez + ew;
#pragma unroll
  for (int off = 1; off < 64; off <<= 1) s += __shfl_xor(s, off);
  float inv = 1.0f / s;
  ((float4*)(outp + (size_t)gw * HDIM))[lane] = make_float4(ex * inv, ey * inv, ez * inv, ew * inv);
}

// ---------------- launch ----------------

extern "C" void kernel_launch(void* const* d_in, const int* in_sizes, int n_in,
                              void* d_out, int out_size, void* d_ws, size_t ws_size,
                              hipStream_t stream) {
  const float* x   = (const float*)d_in[0];
  const int*   ei  = (const int*)d_in[1];
  const float* W1  = (const float*)d_in[2];
  const float* b1  = (const float*)d_in[3];
  const float* Wg1 = (const float*)d_in[4];
  const float* bg1 = (const float*)d_in[5];
  const float* Wg2 = (const float*)d_in[6];
  const float* bg2 = (const float*)d_in[7];
  const float* W2  = (const float*)d_in[8];
  const float* b2  = (const float*)d_in[9];
  const float* W3  = (const float*)d_in[10];
  const float* b3  = (const float*)d_in[11];
  float* out = (float*)d_out;

  const int K1 = in_sizes[2] / HDIM;  // 128
  const int N  = in_sizes[0] / K1;    // 50000
  const int E  = in_sizes[1] / 2;     // 300000

  char* w = (char*)d_ws;
  auto alloc = [&](size_t bytes) -> char* {
    char* p = w;
    w += (bytes + 255) & ~(size_t)255;
    return p;
  };
  // activation planes (hi/lo bf16). PH,PL contiguous so they can alias a 51.2MB fp32 buffer.
  unsigned short* PH = (unsigned short*)alloc((size_t)N * HDIM * 2);
  unsigned short* PL = (unsigned short*)alloc((size_t)N * HDIM * 2);
  float* dinv   = (float*)alloc((size_t)N * sizeof(float));
  int*   deg    = (int*)alloc((size_t)N * sizeof(int));
  int*   rowptr = (int*)alloc((size_t)(N + 1) * sizeof(int));
  int*   cursor = (int*)alloc((size_t)N * sizeof(int));
  int*   col    = (int*)alloc((size_t)E * sizeof(int));
  const int nb  = (N + 255) / 256;
  int*   bsum   = (int*)alloc((size_t)nb * sizeof(int));
  int*   boff   = (int*)alloc((size_t)nb * sizeof(int));
  // staged split weights
  unsigned short* W1sH  = (unsigned short*)alloc((size_t)HDIM * K1 * 2);
  unsigned short* W1sL  = (unsigned short*)alloc((size_t)HDIM * K1 * 2);
  unsigned short* Wg1sH = (unsigned short*)alloc((size_t)HDIM * HDIM * 2);
  unsigned short* Wg1sL = (unsigned short*)alloc((size_t)HDIM * HDIM * 2);
  unsigned short* Wg2sH = (unsigned short*)alloc((size_t)HDIM * HDIM * 2);
  unsigned short* Wg2sL = (unsigned short*)alloc((size_t)HDIM * HDIM * 2);
  unsigned short* W2sH  = (unsigned short*)alloc((size_t)HDIM * HDIM * 2);
  unsigned short* W2sL  = (unsigned short*)alloc((size_t)HDIM * HDIM * 2);
  unsigned short* W3sH  = (unsigned short*)alloc((size_t)HDIM * HDIM * 2);
  unsigned short* W3sL  = (unsigned short*)alloc((size_t)HDIM * HDIM * 2);

  // h3 planes live in d_out's bytes (N*256 fp32 = 2 bf16 planes exactly)
  unsigned short* QH = (unsigned short*)out;
  unsigned short* QL = QH + (size_t)N * HDIM;
  // logits fp32 scratch lives in the PH+PL region (51.2MB contiguous)
  float* logitsBuf = (float*)PH;

  const int ge = (E + 255) / 256;
  const int gn = (N + 255) / 256;

  prep_w_staged<<<(K1 * 32 + 255) / 256, 256, 0, stream>>>(W1, W1sH, W1sL, K1);
  prep_w_staged<<<(HDIM * 32 + 255) / 256, 256, 0, stream>>>(Wg1, Wg1sH, Wg1sL, HDIM);
  prep_w_staged<<<(HDIM * 32 + 255) / 256, 256, 0, stream>>>(Wg2, Wg2sH, Wg2sL, HDIM);
  prep_w_staged<<<(HDIM * 32 + 255) / 256, 256, 0, stream>>>(W2, W2sH, W2sL, HDIM);
  prep_w_staged<<<(HDIM * 32 + 255) / 256, 256, 0, stream>>>(W3, W3sH, W3sL, HDIM);

  hipMemsetAsync(deg, 0, (size_t)N * sizeof(int), stream);
  deg_count_kernel<<<ge, 256, 0, stream>>>(ei, deg, E);
  dinv_kernel<<<gn, 256, 0, stream>>>(deg, dinv, N);
  block_sum_kernel<<<nb, 256, 0, stream>>>(deg, bsum, N);
  scan_bsums_kernel<<<1, 256, 0, stream>>>(bsum, boff, rowptr, nb, N);
  scan_final_kernel<<<nb, 256, 0, stream>>>(deg, boff, rowptr, cursor, N);
  fill_csr_kernel<<<ge, 256, 0, stream>>>(ei, cursor, col, E);

  dim3 ggrid(2, (N + 127) / 128);
  const int gagg = (N + 3) / 4;

  // h0 = relu(x@W1+b1) -> planes P
  mfma_gemm_splitA<true, true><<<ggrid, 256, 0, stream>>>(x, W1sH, W1sL, b1, PH, PL, N, K1);
  // t1 = h0@Wg1 -> out (fp32 scratch in d_out)
  mfma_gemm_p<false, false, false><<<ggrid, 256, 0, stream>>>(PH, PL, Wg1sH, Wg1sL, nullptr, out, nullptr, nullptr, N, HDIM);
  // h1 = relu(agg(t1)+bg1) -> planes P
  aggregate_p<<<gagg, 256, 0, stream>>>(out, dinv, rowptr, col, bg1, PH, PL, N);
  // t2 = h1@Wg2 -> out
  mfma_gemm_p<false, false, false><<<ggrid, 256, 0, stream>>>(PH, PL, Wg2sH, Wg2sL, nullptr, out, nullptr, nullptr, N, HDIM);
  // h2 = relu(agg(t2)+bg2) -> planes P
  aggregate_p<<<gagg, 256, 0, stream>>>(out, dinv, rowptr, col, bg2, PH, PL, N);
  // h3 = relu(h2@W2+b2) -> planes Q (in d_out bytes; P stays intact during reads)
  mfma_gemm_p<true, true, true><<<ggrid, 256, 0, stream>>>(PH, PL, W2sH, W2sL, b2, nullptr, QH, QL, N, HDIM);
  // logits = h3@W3+b3 -> logitsBuf (PH/PL region, h2 planes dead now)
  mfma_gemm_p<true, false, false><<<ggrid, 256, 0, stream>>>(QH, QL, W3sH, W3sL, b3, logitsBuf, nullptr, nullptr, N, HDIM);
  // out = softmax(logits)
  softmax_kernel<<<gagg, 256, 0, stream>>>(logitsBuf, out, N);
}

// Round 6
// 425.399 us; speedup vs baseline: 1.3927x; 1.0207x over previous
//
#include <hip/hip_runtime.h>
#include <math.h>

#define HDIM 256

typedef float floatx4 __attribute__((ext_vector_type(4)));
typedef __bf16 bf16x8 __attribute__((ext_vector_type(8)));
typedef unsigned short ushortx4 __attribute__((ext_vector_type(4)));

#define AS1C(p) ((const __attribute__((address_space(1))) void*)(p))
#define AS3(p)  ((__attribute__((address_space(3))) void*)(p))

__device__ inline unsigned short bf16_rn(float f) {
  unsigned u = __float_as_uint(f);
  return (unsigned short)((u + 0x7FFFu + ((u >> 16) & 1u)) >> 16);
}

__device__ inline void split_f32(float f, unsigned short& h, unsigned short& l) {
  unsigned short hb = bf16_rn(f);
  float hf = __uint_as_float(((unsigned)hb) << 16);
  h = hb;
  l = bf16_rn(f - hf);
}

// ---------------- weight prep: W[K][256] fp32 -> staged hi/lo bf16 in tile order ----------------
// idx = ((cb*(K/32) + kt)*512 + kc*128 + col); chunk = W[kt*32+kc*8 + e][cb*128+col], e=0..7.

__global__ __launch_bounds__(256)
void prep_w_staged(const float* __restrict__ W, unsigned short* __restrict__ SH,
                   unsigned short* __restrict__ SL, int K) {
  int idx = blockIdx.x * 256 + threadIdx.x;
  int total = K * 32;
  if (idx >= total) return;
  int chunksPerCb = total >> 1;
  int cb = (idx >= chunksPerCb) ? 1 : 0;
  int rem = idx - cb * chunksPerCb;
  int kt = rem >> 9;
  int chunk = rem & 511;
  int kc = chunk >> 7;
  int col = chunk & 127;
  const float* src = W + (size_t)(kt * 32 + kc * 8) * HDIM + cb * 128 + col;
#pragma unroll
  for (int e = 0; e < 8; ++e) {
    unsigned short h, l;
    split_f32(src[(size_t)e * HDIM], h, l);
    SH[(size_t)idx * 8 + e] = h;
    SL[(size_t)idx * 8 + e] = l;
  }
}

// ---------------- CSR build ----------------

__global__ __launch_bounds__(256)
void deg_count_kernel(const int* __restrict__ ei, int* __restrict__ deg, int E) {
  int e = blockIdx.x * 256 + threadIdx.x;
  if (e < E) atomicAdd(&deg[ei[E + e]], 1);
}

__global__ __launch_bounds__(256)
void dinv_kernel(const int* __restrict__ deg, float* __restrict__ dinv, int n) {
  int i = blockIdx.x * 256 + threadIdx.x;
  if (i < n) dinv[i] = 1.0f / sqrtf((float)deg[i] + 1.0f);
}

__global__ __launch_bounds__(256)
void block_sum_kernel(const int* __restrict__ deg, int* __restrict__ bsum, int n) {
  __shared__ int sm[256];
  int t = threadIdx.x;
  int idx = blockIdx.x * 256 + t;
  sm[t] = (idx < n) ? deg[idx] : 0;
  __syncthreads();
  for (int off = 128; off > 0; off >>= 1) {
    if (t < off) sm[t] += sm[t + off];
    __syncthreads();
  }
  if (t == 0) bsum[blockIdx.x] = sm[0];
}

__global__ __launch_bounds__(256)
void scan_bsums_kernel(const int* __restrict__ bsum, int* __restrict__ boff,
                       int* __restrict__ rowptr, int nb, int n) {
  __shared__ int sm[256];
  int t = threadIdx.x;
  int v = (t < nb) ? bsum[t] : 0;
  sm[t] = v;
  __syncthreads();
  for (int off = 1; off < 256; off <<= 1) {
    int a = (t >= off) ? sm[t - off] : 0;
    __syncthreads();
    sm[t] += a;
    __syncthreads();
  }
  if (t < nb) boff[t] = sm[t] - v;
  if (t == 255) rowptr[n] = sm[255];
}

__global__ __launch_bounds__(256)
void scan_final_kernel(const int* __restrict__ deg, const int* __restrict__ boff,
                       int* __restrict__ rowptr, int* __restrict__ cursor, int n) {
  __shared__ int sm[256];
  int t = threadIdx.x;
  int idx = blockIdx.x * 256 + t;
  int v = (idx < n) ? deg[idx] : 0;
  sm[t] = v;
  __syncthreads();
  for (int off = 1; off < 256; off <<= 1) {
    int a = (t >= off) ? sm[t - off] : 0;
    __syncthreads();
    sm[t] += a;
    __syncthreads();
  }
  int excl = sm[t] - v + boff[blockIdx.x];
  if (idx < n) { rowptr[idx] = excl; cursor[idx] = excl; }
}

__global__ __launch_bounds__(256)
void fill_csr_kernel(const int* __restrict__ ei, int* __restrict__ cursor,
                     int* __restrict__ col, int E) {
  int e = blockIdx.x * 256 + threadIdx.x;
  if (e < E) {
    int s = ei[e];
    int d = ei[E + e];
    int p = atomicAdd(&cursor[d], 1);
    col[p] = s;
  }
}

// ---------------- GEMM 1: A fp32 (split in-kernel), tile 128x128, staged B, writes planes ----------------

template<bool BIAS, bool RELU>
__global__ __launch_bounds__(256, 3)
void mfma_gemm_splitA(const float* __restrict__ A,
                      const unsigned short* __restrict__ SWH,
                      const unsigned short* __restrict__ SWL,
                      const float* __restrict__ bias,
                      unsigned short* __restrict__ CH, unsigned short* __restrict__ CL,
                      int M, int K) {
  __shared__ __align__(16) unsigned short AsH[128 * 40];
  __shared__ __align__(16) unsigned short AsL[128 * 40];
  __shared__ __align__(16) unsigned short BsH[4096];
  __shared__ __align__(16) unsigned short BsL[4096];

  const int tid = threadIdx.x;
  const int w = tid >> 6;
  const int l = tid & 63;
  const int l15 = l & 15;
  const int quad = l >> 4;
  const int wm = w & 1;
  const int wn = w >> 1;
  const int bm = blockIdx.y * 128;
  const int bn = blockIdx.x * 128;
  const int ktc = K >> 5;

  floatx4 acc[4][4];
#pragma unroll
  for (int i = 0; i < 4; ++i)
#pragma unroll
    for (int j = 0; j < 4; ++j) acc[i][j] = (floatx4){0.f, 0.f, 0.f, 0.f};

  for (int kt = 0; kt < ktc; ++kt) {
    int k0 = kt * 32;
    float4 av[4];
#pragma unroll
    for (int i = 0; i < 4; ++i) {
      int chunk = i * 256 + tid;
      int row = chunk >> 3;
      int kc4 = chunk & 7;
      int grow = bm + row;
      if (grow > M - 1) grow = M - 1;
      av[i] = *(const float4*)(A + (size_t)grow * K + k0 + kc4 * 4);
    }

    __syncthreads();

    size_t wb = ((size_t)(blockIdx.x * ktc + kt)) * 4096;
#pragma unroll
    for (int j = 0; j < 2; ++j) {
      int c = j * 256 + tid;
      __builtin_amdgcn_global_load_lds(AS1C(SWH + wb + (size_t)c * 8),
                                       AS3(&BsH[(j * 256 + w * 64) * 8]), 16, 0, 0);
      __builtin_amdgcn_global_load_lds(AS1C(SWL + wb + (size_t)c * 8),
                                       AS3(&BsL[(j * 256 + w * 64) * 8]), 16, 0, 0);
    }

#pragma unroll
    for (int i = 0; i < 4; ++i) {
      int chunk = i * 256 + tid;
      int row = chunk >> 3;
      int kc4 = chunk & 7;
      unsigned short h0, h1, h2, h3, l0, l1, l2, l3;
      split_f32(av[i].x, h0, l0);
      split_f32(av[i].y, h1, l1);
      split_f32(av[i].z, h2, l2);
      split_f32(av[i].w, h3, l3);
      *(ushortx4*)&AsH[row * 40 + kc4 * 4] = (ushortx4){h0, h1, h2, h3};
      *(ushortx4*)&AsL[row * 40 + kc4 * 4] = (ushortx4){l0, l1, l2, l3};
    }

    __syncthreads();

    bf16x8 aH[4], aL[4];
#pragma unroll
    for (int fi = 0; fi < 4; ++fi) {
      int row = wm * 64 + fi * 16 + l15;
      aH[fi] = *(const bf16x8*)&AsH[row * 40 + quad * 8];
      aL[fi] = *(const bf16x8*)&AsL[row * 40 + quad * 8];
    }
#pragma unroll
    for (int fj = 0; fj < 4; ++fj) {
      int colL = wn * 64 + fj * 16 + l15;
      int cidx = quad * 128 + colL;
      bf16x8 bh = *(const bf16x8*)&BsH[cidx * 8];
      bf16x8 bl = *(const bf16x8*)&BsL[cidx * 8];
#pragma unroll
      for (int fi = 0; fi < 4; ++fi) {
        floatx4 t = acc[fi][fj];
        t = __builtin_amdgcn_mfma_f32_16x16x32_bf16(aH[fi], bl, t, 0, 0, 0);
        t = __builtin_amdgcn_mfma_f32_16x16x32_bf16(aL[fi], bh, t, 0, 0, 0);
        t = __builtin_amdgcn_mfma_f32_16x16x32_bf16(aH[fi], bh, t, 0, 0, 0);
        acc[fi][fj] = t;
      }
    }
  }

  float bcol[4];
#pragma unroll
  for (int fj = 0; fj < 4; ++fj)
    bcol[fj] = BIAS ? bias[bn + wn * 64 + fj * 16 + l15] : 0.f;

#pragma unroll
  for (int fi = 0; fi < 4; ++fi) {
    int rb = bm + wm * 64 + fi * 16 + quad * 4;
#pragma unroll
    for (int r = 0; r < 4; ++r) {
      int row = rb + r;
      if (row < M) {
        size_t base = (size_t)row * HDIM + bn + wn * 64 + l15;
#pragma unroll
        for (int fj = 0; fj < 4; ++fj) {
          float v = acc[fi][fj][r] + bcol[fj];
          if (RELU) v = fmaxf(v, 0.f);
          unsigned short h, lo;
          split_f32(v, h, lo);
          CH[base + fj * 16] = h;
          CL[base + fj * 16] = lo;
        }
      }
    }
  }
}

// ---------------- plane GEMM: A hi/lo planes + staged B, all via global_load_lds ----------------

template<bool BIAS, bool RELU, bool SPLIT_OUT>
__global__ __launch_bounds__(256, 3)
void mfma_gemm_p(const unsigned short* __restrict__ AH, const unsigned short* __restrict__ AL,
                 const unsigned short* __restrict__ SWH, const unsigned short* __restrict__ SWL,
                 const float* __restrict__ bias,
                 float* __restrict__ C, unsigned short* __restrict__ CH,
                 unsigned short* __restrict__ CL, int M, int K) {
  __shared__ __align__(16) unsigned short AsH[4096];
  __shared__ __align__(16) unsigned short AsL[4096];
  __shared__ __align__(16) unsigned short BsH[4096];
  __shared__ __align__(16) unsigned short BsL[4096];

  const int tid = threadIdx.x;
  const int w = tid >> 6;
  const int l = tid & 63;
  const int l15 = l & 15;
  const int quad = l >> 4;
  const int wm = w & 1;
  const int wn = w >> 1;
  const int bm = blockIdx.y * 128;
  const int bn = blockIdx.x * 128;
  const int ktc = K >> 5;

  floatx4 acc[4][4];
#pragma unroll
  for (int i = 0; i < 4; ++i)
#pragma unroll
    for (int j = 0; j < 4; ++j) acc[i][j] = (floatx4){0.f, 0.f, 0.f, 0.f};

  for (int kt = 0; kt < ktc; ++kt) {
    __syncthreads();

#pragma unroll
    for (int i = 0; i < 2; ++i) {
      int L = i * 256 + tid;
      int row = L >> 2;
      int p = L & 3;
      int kc = p ^ (row & 3) ^ ((row >> 2) & 3);
      int grow = bm + row;
      if (grow > M - 1) grow = M - 1;
      const unsigned short* gH = AH + (size_t)grow * K + kt * 32 + kc * 8;
      const unsigned short* gL = AL + (size_t)grow * K + kt * 32 + kc * 8;
      __builtin_amdgcn_global_load_lds(AS1C(gH), AS3(&AsH[(i * 256 + w * 64) * 8]), 16, 0, 0);
      __builtin_amdgcn_global_load_lds(AS1C(gL), AS3(&AsL[(i * 256 + w * 64) * 8]), 16, 0, 0);
    }
    size_t wb = ((size_t)(blockIdx.x * ktc + kt)) * 4096;
#pragma unroll
    for (int j = 0; j < 2; ++j) {
      int c = j * 256 + tid;
      __builtin_amdgcn_global_load_lds(AS1C(SWH + wb + (size_t)c * 8),
                                       AS3(&BsH[(j * 256 + w * 64) * 8]), 16, 0, 0);
      __builtin_amdgcn_global_load_lds(AS1C(SWL + wb + (size_t)c * 8),
                                       AS3(&BsL[(j * 256 + w * 64) * 8]), 16, 0, 0);
    }

    __syncthreads();

    bf16x8 aH[4], aL[4];
#pragma unroll
    for (int fi = 0; fi < 4; ++fi) {
      int r = wm * 64 + fi * 16 + l15;
      int sw = quad ^ (r & 3) ^ ((r >> 2) & 3);
      aH[fi] = *(const bf16x8*)&AsH[(r * 4 + sw) * 8];
      aL[fi] = *(const bf16x8*)&AsL[(r * 4 + sw) * 8];
    }
#pragma unroll
    for (int fj = 0; fj < 4; ++fj) {
      int colL = wn * 64 + fj * 16 + l15;
      int cidx = quad * 128 + colL;
      bf16x8 bh = *(const bf16x8*)&BsH[cidx * 8];
      bf16x8 bl = *(const bf16x8*)&BsL[cidx * 8];
#pragma unroll
      for (int fi = 0; fi < 4; ++fi) {
        floatx4 t = acc[fi][fj];
        t = __builtin_amdgcn_mfma_f32_16x16x32_bf16(aH[fi], bl, t, 0, 0, 0);
        t = __builtin_amdgcn_mfma_f32_16x16x32_bf16(aL[fi], bh, t, 0, 0, 0);
        t = __builtin_amdgcn_mfma_f32_16x16x32_bf16(aH[fi], bh, t, 0, 0, 0);
        acc[fi][fj] = t;
      }
    }
  }

  float bcol[4];
#pragma unroll
  for (int fj = 0; fj < 4; ++fj)
    bcol[fj] = BIAS ? bias[bn + wn * 64 + fj * 16 + l15] : 0.f;

#pragma unroll
  for (int fi = 0; fi < 4; ++fi) {
    int rb = bm + wm * 64 + fi * 16 + quad * 4;
#pragma unroll
    for (int r = 0; r < 4; ++r) {
      int row = rb + r;
      if (row < M) {
        size_t base = (size_t)row * HDIM + bn + wn * 64 + l15;
        if (SPLIT_OUT) {
#pragma unroll
          for (int fj = 0; fj < 4; ++fj) {
            float v = acc[fi][fj][r] + bcol[fj];
            if (RELU) v = fmaxf(v, 0.f);
            unsigned short h, lo;
            split_f32(v, h, lo);
            CH[base + fj * 16] = h;
            CL[base + fj * 16] = lo;
          }
        } else {
#pragma unroll
          for (int fj = 0; fj < 4; ++fj) {
            float v = acc[fi][fj][r] + bcol[fj];
            if (RELU) v = fmaxf(v, 0.f);
            C[base + fj * 16] = v;
          }
        }
      }
    }
  }
}

// ---------------- fused GEMM + softmax: tile 128x256, 512 threads, in-place safe ----------------
// out = softmax(A@W + b) rows bm..bm+127. BN=256 => each row fully within one block.

__global__ __launch_bounds__(512, 4)
void mfma_gemm_softmax(const unsigned short* __restrict__ AH, const unsigned short* __restrict__ AL,
                       const unsigned short* __restrict__ SWH, const unsigned short* __restrict__ SWL,
                       const float* __restrict__ bias, float* __restrict__ out, int M, int K) {
  __shared__ __align__(16) unsigned short AsH[4096];   // 512 chunks
  __shared__ __align__(16) unsigned short AsL[4096];
  __shared__ __align__(16) unsigned short BsH[8192];   // 1024 chunks: kc*256 + col
  __shared__ __align__(16) unsigned short BsL[8192];
  __shared__ float smax[128 * 4];
  __shared__ float ssum[128 * 4];

  const int tid = threadIdx.x;
  const int w = tid >> 6;        // 0..7
  const int l = tid & 63;
  const int l15 = l & 15;
  const int quad = l >> 4;
  const int wm = w & 1;          // row stripe of 64
  const int wn = w >> 1;         // col stripe of 64 (0..3)
  const int bm = blockIdx.x * 128;
  const int ktc = K >> 5;
  const int chunksPerCb = ktc * 512;

  floatx4 acc[4][4];
#pragma unroll
  for (int i = 0; i < 4; ++i)
#pragma unroll
    for (int j = 0; j < 4; ++j) acc[i][j] = (floatx4){0.f, 0.f, 0.f, 0.f};

  for (int kt = 0; kt < ktc; ++kt) {
    __syncthreads();

    // A: 512 chunks/plane, 1 per thread
    {
      int L = tid;
      int row = L >> 2;
      int p = L & 3;
      int kc = p ^ (row & 3) ^ ((row >> 2) & 3);
      int grow = bm + row;
      if (grow > M - 1) grow = M - 1;
      const unsigned short* gH = AH + (size_t)grow * K + kt * 32 + kc * 8;
      const unsigned short* gL = AL + (size_t)grow * K + kt * 32 + kc * 8;
      __builtin_amdgcn_global_load_lds(AS1C(gH), AS3(&AsH[(w * 64) * 8]), 16, 0, 0);
      __builtin_amdgcn_global_load_lds(AS1C(gL), AS3(&AsL[(w * 64) * 8]), 16, 0, 0);
    }
    // B: 1024 chunks/plane, 2 per thread; pos = kc*256 + cb*128 + colL
#pragma unroll
    for (int j = 0; j < 2; ++j) {
      int pos = j * 512 + w * 64 + l;
      int kc = pos >> 8;
      int within = pos & 255;
      int cb = within >> 7;
      int colL = within & 127;
      size_t gi = (size_t)cb * chunksPerCb + (size_t)kt * 512 + kc * 128 + colL;
      __builtin_amdgcn_global_load_lds(AS1C(SWH + gi * 8),
                                       AS3(&BsH[(j * 512 + w * 64) * 8]), 16, 0, 0);
      __builtin_amdgcn_global_load_lds(AS1C(SWL + gi * 8),
                                       AS3(&BsL[(j * 512 + w * 64) * 8]), 16, 0, 0);
    }

    __syncthreads();

    bf16x8 aH[4], aL[4];
#pragma unroll
    for (int fi = 0; fi < 4; ++fi) {
      int r = wm * 64 + fi * 16 + l15;
      int sw = quad ^ (r & 3) ^ ((r >> 2) & 3);
      aH[fi] = *(const bf16x8*)&AsH[(r * 4 + sw) * 8];
      aL[fi] = *(const bf16x8*)&AsL[(r * 4 + sw) * 8];
    }
#pragma unroll
    for (int fj = 0; fj < 4; ++fj) {
      int colG = wn * 64 + fj * 16 + l15;     // 0..255
      int cidx = quad * 256 + colG;
      bf16x8 bh = *(const bf16x8*)&BsH[cidx * 8];
      bf16x8 bl = *(const bf16x8*)&BsL[cidx * 8];
#pragma unroll
      for (int fi = 0; fi < 4; ++fi) {
        floatx4 t = acc[fi][fj];
        t = __builtin_amdgcn_mfma_f32_16x16x32_bf16(aH[fi], bl, t, 0, 0, 0);
        t = __builtin_amdgcn_mfma_f32_16x16x32_bf16(aL[fi], bh, t, 0, 0, 0);
        t = __builtin_amdgcn_mfma_f32_16x16x32_bf16(aH[fi], bh, t, 0, 0, 0);
        acc[fi][fj] = t;
      }
    }
  }

  float bcol[4];
#pragma unroll
  for (int fj = 0; fj < 4; ++fj)
    bcol[fj] = bias[wn * 64 + fj * 16 + l15];

  // phase 1: per-row max (wave-local over 64 cols, then LDS across 4 wn-waves)
#pragma unroll
  for (int fi = 0; fi < 4; ++fi) {
#pragma unroll
    for (int r = 0; r < 4; ++r) {
      float mv = -3.4e38f;
#pragma unroll
      for (int fj = 0; fj < 4; ++fj) mv = fmaxf(mv, acc[fi][fj][r] + bcol[fj]);
#pragma unroll
      for (int off = 1; off < 16; off <<= 1) mv = fmaxf(mv, __shfl_xor(mv, off));
      int row = wm * 64 + fi * 16 + quad * 4 + r;
      if (l15 == 0) smax[row * 4 + wn] = mv;
    }
  }
  __syncthreads();

  // phase 2: exp + per-row sum
#pragma unroll
  for (int fi = 0; fi < 4; ++fi) {
#pragma unroll
    for (int r = 0; r < 4; ++r) {
      int row = wm * 64 + fi * 16 + quad * 4 + r;
      float gm = fmaxf(fmaxf(smax[row * 4 + 0], smax[row * 4 + 1]),
                       fmaxf(smax[row * 4 + 2], smax[row * 4 + 3]));
      float s = 0.f;
#pragma unroll
      for (int fj = 0; fj < 4; ++fj) {
        float p = expf(acc[fi][fj][r] + bcol[fj] - gm);
        acc[fi][fj][r] = p;
        s += p;
      }
#pragma unroll
      for (int off = 1; off < 16; off <<= 1) s += __shfl_xor(s, off);
      if (l15 == 0) ssum[row * 4 + wn] = s;
    }
  }
  __syncthreads();

  // phase 3: normalize + store
#pragma unroll
  for (int fi = 0; fi < 4; ++fi) {
#pragma unroll
    for (int r = 0; r < 4; ++r) {
      int row = wm * 64 + fi * 16 + quad * 4 + r;
      int grow = bm + row;
      if (grow < M) {
        float inv = 1.0f / (ssum[row * 4 + 0] + ssum[row * 4 + 1] +
                            ssum[row * 4 + 2] + ssum[row * 4 + 3]);
        float* Cp = out + (size_t)grow * HDIM + wn * 64 + l15;
#pragma unroll
        for (int fj = 0; fj < 4; ++fj) Cp[fj * 16] = acc[fi][fj][r] * inv;
      }
    }
  }
}

// ---------------- GCN aggregation: two-phase batched gather (MLP~8), plane output ----------------

__global__ __launch_bounds__(256)
void aggregate_b(const float* __restrict__ t, const float* __restrict__ dinv,
                 const int* __restrict__ rowptr, const int* __restrict__ col,
                 const float* __restrict__ bias,
                 unsigned short* __restrict__ OH, unsigned short* __restrict__ OL, int n) {
  int gw = (int)((blockIdx.x * 256 + threadIdx.x) >> 6);
  int lane = threadIdx.x & 63;
  if (gw >= n) return;
  float di = dinv[gw];
  float4 v = ((const float4*)(t + (size_t)gw * HDIM))[lane];
  float ss = di * di;
  float a0 = v.x * ss, a1 = v.y * ss, a2 = v.z * ss, a3 = v.w * ss;
  int e0 = rowptr[gw], e1 = rowptr[gw + 1];

  for (int base = e0; base < e1; base += 8) {
    // phase A: 8 independent col loads (tail clamped to last valid edge)
    int cs[8];
#pragma unroll
    for (int i = 0; i < 8; ++i) {
      int e = base + i;
      if (e > e1 - 1) e = e1 - 1;
      cs[i] = col[e];
    }
    // phase B: 8 independent dinv loads; tail weight -> 0 (cndmask, no branch)
    float wg[8];
#pragma unroll
    for (int i = 0; i < 8; ++i)
      wg[i] = (base + i < e1) ? dinv[cs[i]] * di : 0.f;
    // phase C: 8 independent row gathers
    float4 rw[8];
#pragma unroll
    for (int i = 0; i < 8; ++i)
      rw[i] = ((const float4*)(t + (size_t)cs[i] * HDIM))[lane];
    // phase D: accumulate
#pragma unroll
    for (int i = 0; i < 8; ++i) {
      a0 = fmaf(rw[i].x, wg[i], a0);
      a1 = fmaf(rw[i].y, wg[i], a1);
      a2 = fmaf(rw[i].z, wg[i], a2);
      a3 = fmaf(rw[i].w, wg[i], a3);
    }
  }

  float4 bb = ((const float4*)bias)[lane];
  float r0 = fmaxf(a0 + bb.x, 0.f);
  float r1 = fmaxf(a1 + bb.y, 0.f);
  float r2 = fmaxf(a2 + bb.z, 0.f);
  float r3 = fmaxf(a3 + bb.w, 0.f);
  unsigned short h0, h1, h2, h3, l0, l1, l2, l3;
  split_f32(r0, h0, l0);
  split_f32(r1, h1, l1);
  split_f32(r2, h2, l2);
  split_f32(r3, h3, l3);
  ((ushortx4*)(OH + (size_t)gw * HDIM))[lane] = (ushortx4){h0, h1, h2, h3};
  ((ushortx4*)(OL + (size_t)gw * HDIM))[lane] = (ushortx4){l0, l1, l2, l3};
}

// ---------------- launch ----------------

extern "C" void kernel_launch(void* const* d_in, const int* in_sizes, int n_in,
                              void* d_out, int out_size, void* d_ws, size_t ws_size,
                              hipStream_t stream) {
  const float* x   = (const float*)d_in[0];
  const int*   ei  = (const int*)d_in[1];
  const float* W1  = (const float*)d_in[2];
  const float* b1  = (const float*)d_in[3];
  const float* Wg1 = (const float*)d_in[4];
  const float* bg1 = (const float*)d_in[5];
  const float* Wg2 = (const float*)d_in[6];
  const float* bg2 = (const float*)d_in[7];
  const float* W2  = (const float*)d_in[8];
  const float* b2  = (const float*)d_in[9];
  const float* W3  = (const float*)d_in[10];
  const float* b3  = (const float*)d_in[11];
  float* out = (float*)d_out;

  const int K1 = in_sizes[2] / HDIM;  // 128
  const int N  = in_sizes[0] / K1;    // 50000
  const int E  = in_sizes[1] / 2;     // 300000

  char* w = (char*)d_ws;
  auto alloc = [&](size_t bytes) -> char* {
    char* p = w;
    w += (bytes + 255) & ~(size_t)255;
    return p;
  };
  unsigned short* PH = (unsigned short*)alloc((size_t)N * HDIM * 2);
  unsigned short* PL = (unsigned short*)alloc((size_t)N * HDIM * 2);
  float* dinv   = (float*)alloc((size_t)N * sizeof(float));
  int*   deg    = (int*)alloc((size_t)N * sizeof(int));
  int*   rowptr = (int*)alloc((size_t)(N + 1) * sizeof(int));
  int*   cursor = (int*)alloc((size_t)N * sizeof(int));
  int*   col    = (int*)alloc((size_t)E * sizeof(int));
  const int nb  = (N + 255) / 256;
  int*   bsum   = (int*)alloc((size_t)nb * sizeof(int));
  int*   boff   = (int*)alloc((size_t)nb * sizeof(int));
  unsigned short* W1sH  = (unsigned short*)alloc((size_t)HDIM * K1 * 2);
  unsigned short* W1sL  = (unsigned short*)alloc((size_t)HDIM * K1 * 2);
  unsigned short* Wg1sH = (unsigned short*)alloc((size_t)HDIM * HDIM * 2);
  unsigned short* Wg1sL = (unsigned short*)alloc((size_t)HDIM * HDIM * 2);
  unsigned short* Wg2sH = (unsigned short*)alloc((size_t)HDIM * HDIM * 2);
  unsigned short* Wg2sL = (unsigned short*)alloc((size_t)HDIM * HDIM * 2);
  unsigned short* W2sH  = (unsigned short*)alloc((size_t)HDIM * HDIM * 2);
  unsigned short* W2sL  = (unsigned short*)alloc((size_t)HDIM * HDIM * 2);
  unsigned short* W3sH  = (unsigned short*)alloc((size_t)HDIM * HDIM * 2);
  unsigned short* W3sL  = (unsigned short*)alloc((size_t)HDIM * HDIM * 2);

  // h3 planes live in d_out's bytes (N*256 fp32 = exactly 2 bf16 planes)
  unsigned short* QH = (unsigned short*)out;
  unsigned short* QL = QH + (size_t)N * HDIM;

  const int ge = (E + 255) / 256;
  const int gn = (N + 255) / 256;

  prep_w_staged<<<(K1 * 32 + 255) / 256, 256, 0, stream>>>(W1, W1sH, W1sL, K1);
  prep_w_staged<<<(HDIM * 32 + 255) / 256, 256, 0, stream>>>(Wg1, Wg1sH, Wg1sL, HDIM);
  prep_w_staged<<<(HDIM * 32 + 255) / 256, 256, 0, stream>>>(Wg2, Wg2sH, Wg2sL, HDIM);
  prep_w_staged<<<(HDIM * 32 + 255) / 256, 256, 0, stream>>>(W2, W2sH, W2sL, HDIM);
  prep_w_staged<<<(HDIM * 32 + 255) / 256, 256, 0, stream>>>(W3, W3sH, W3sL, HDIM);

  hipMemsetAsync(deg, 0, (size_t)N * sizeof(int), stream);
  deg_count_kernel<<<ge, 256, 0, stream>>>(ei, deg, E);
  dinv_kernel<<<gn, 256, 0, stream>>>(deg, dinv, N);
  block_sum_kernel<<<nb, 256, 0, stream>>>(deg, bsum, N);
  scan_bsums_kernel<<<1, 256, 0, stream>>>(bsum, boff, rowptr, nb, N);
  scan_final_kernel<<<nb, 256, 0, stream>>>(deg, boff, rowptr, cursor, N);
  fill_csr_kernel<<<ge, 256, 0, stream>>>(ei, cursor, col, E);

  dim3 ggrid(2, (N + 127) / 128);
  const int gagg = (N + 3) / 4;
  const int gfuse = (N + 127) / 128;

  // h0 = relu(x@W1+b1) -> planes P
  mfma_gemm_splitA<true, true><<<ggrid, 256, 0, stream>>>(x, W1sH, W1sL, b1, PH, PL, N, K1);
  // t1 = h0@Wg1 -> out (fp32 scratch in d_out)
  mfma_gemm_p<false, false, false><<<ggrid, 256, 0, stream>>>(PH, PL, Wg1sH, Wg1sL, nullptr, out, nullptr, nullptr, N, HDIM);
  // h1 = relu(agg(t1)+bg1) -> planes P
  aggregate_b<<<gagg, 256, 0, stream>>>(out, dinv, rowptr, col, bg1, PH, PL, N);
  // t2 = h1@Wg2 -> out
  mfma_gemm_p<false, false, false><<<ggrid, 256, 0, stream>>>(PH, PL, Wg2sH, Wg2sL, nullptr, out, nullptr, nullptr, N, HDIM);
  // h2 = relu(agg(t2)+bg2) -> planes P
  aggregate_b<<<gagg, 256, 0, stream>>>(out, dinv, rowptr, col, bg2, PH, PL, N);
  // h3 = relu(h2@W2+b2) -> planes Q (d_out bytes)
  mfma_gemm_p<true, true, true><<<ggrid, 256, 0, stream>>>(PH, PL, W2sH, W2sL, b2, nullptr, QH, QL, N, HDIM);
  // out = softmax(h3@W3+b3), fused, in-place on d_out (BN=256: block owns its rows)
  mfma_gemm_softmax<<<gfuse, 512, 0, stream>>>(QH, QL, W3sH, W3sL, b3, out, N, HDIM);
}